// Round 4
// baseline (229.853 us; speedup 1.0000x reference)
//
#include <hip/hip_runtime.h>

#define NN 8192
#define CC 512

typedef __attribute__((ext_vector_type(8))) short short8;
typedef __attribute__((ext_vector_type(4))) float f32x4;
typedef unsigned short ushort_t;

__device__ __forceinline__ unsigned short f2bf(float f) {
    unsigned int u = __float_as_uint(f);
    u += 0x7FFF + ((u >> 16) & 1);
    return (unsigned short)(u >> 16);
}

__device__ __forceinline__ void gload_lds16(const void* g, void* l) {
    __builtin_amdgcn_global_load_lds((const __attribute__((address_space(1))) unsigned int*)g,
                                     (__attribute__((address_space(3))) unsigned int*)l,
                                     16, 0, 0);
}

// ---------------- Kernel 1: ds = rsqrt(rowsum(adj)+1);  adj16 = bf16(adj) (fused) ----------------
__global__ __launch_bounds__(256) void k_rowsum_cvt(const float* __restrict__ adj,
                                                    float* __restrict__ ds,
                                                    ushort_t* __restrict__ adj16) {
    int row = blockIdx.x;
    const float4* p = (const float4*)(adj + (size_t)row * NN);
    ushort4* q = (ushort4*)(adj16 + (size_t)row * NN);
    float s = 0.f;
#pragma unroll
    for (int i = 0; i < 8; ++i) {
        float4 v = p[threadIdx.x + i * 256];
        s += (v.x + v.y) + (v.z + v.w);
        ushort4 u;
        u.x = f2bf(v.x); u.y = f2bf(v.y); u.z = f2bf(v.z); u.w = f2bf(v.w);
        q[threadIdx.x + i * 256] = u;
    }
#pragma unroll
    for (int off = 32; off > 0; off >>= 1) s += __shfl_down(s, off, 64);
    __shared__ float partial[4];
    if ((threadIdx.x & 63) == 0) partial[threadIdx.x >> 6] = s;
    __syncthreads();
    if (threadIdx.x == 0) {
        float deg = ((partial[0] + partial[1]) + (partial[2] + partial[3])) + 1.0f;
        ds[row] = rsqrtf(deg);
    }
}

// plain rowsum (fallback path)
__global__ __launch_bounds__(256) void k_rowsum(const float* __restrict__ adj,
                                                float* __restrict__ ds) {
    int row = blockIdx.x;
    const float4* p = (const float4*)(adj + (size_t)row * NN);
    float s = 0.f;
#pragma unroll
    for (int i = 0; i < 8; ++i) {
        float4 v = p[threadIdx.x + i * 256];
        s += (v.x + v.y) + (v.z + v.w);
    }
#pragma unroll
    for (int off = 32; off > 0; off >>= 1) s += __shfl_down(s, off, 64);
    __shared__ float partial[4];
    if ((threadIdx.x & 63) == 0) partial[threadIdx.x >> 6] = s;
    __syncthreads();
    if (threadIdx.x == 0) {
        float deg = ((partial[0] + partial[1]) + (partial[2] + partial[3])) + 1.0f;
        ds[row] = rsqrtf(deg);
    }
}

// ---------------- Kernel 2: out[c][r] = bf16( in[r][c] * (scale ? scale[r] : 1) ) ----------------
__global__ __launch_bounds__(256) void k_transpose(const float* __restrict__ in,
                                                   ushort_t* __restrict__ out,
                                                   const float* __restrict__ scale,
                                                   int R, int C) {
    __shared__ float tile[64][65];
    int r0 = blockIdx.x * 64, c0 = blockIdx.y * 64;
    int t = threadIdx.x;
    int cl = t & 63;
    int rl0 = t >> 6;
#pragma unroll
    for (int i = 0; i < 16; ++i) {
        int r = rl0 + i * 4;
        float v = in[(size_t)(r0 + r) * C + c0 + cl];
        float sc = scale ? scale[r0 + r] : 1.0f;
        tile[r][cl] = v * sc;
    }
    __syncthreads();
#pragma unroll
    for (int i = 0; i < 16; ++i) {
        int c = rl0 + i * 4;
        int r = cl;
        out[(size_t)(c0 + c) * R + r0 + r] = f2bf(tile[r][c]);
    }
}

// ---------------- Kernel 3 (primary): 256x256 tile, BK=32, dbuf, counted-overlap split-K=4 ----------------
// adj16 bf16 [NN][NN]; yt bf16 [CC][NN]; part f32 [4][NN][CC]
// T3 minimum recipe: stage(buf^1, t+1) issued BEFORE compute(buf); one barrier/iter.
__global__ __launch_bounds__(512, 2) void k_gemm1c(const ushort_t* __restrict__ adj16,
                                                   const ushort_t* __restrict__ yt,
                                                   float* __restrict__ part) {
    __shared__ __align__(16) ushort_t As[2][256 * 32];   // 2 x 16 KB
    __shared__ __align__(16) ushort_t Bs[2][256 * 32];   // 2 x 16 KB

    int t = threadIdx.x;
    int wid = t >> 6, lane = t & 63;

    // grid 256 = xcd(8) x slot(32); slot -> cb(2) x u; u = (slot>>1) + 16*xcd in [0,128) -> rb(32) x ks(4)
    int gid = blockIdx.x;
    int xcd = gid & 7, slot = gid >> 3;
    int cb = slot & 1;
    int u = (slot >> 1) + 16 * xcd;
    int rb = u & 31, ks = u >> 5;
    int rowBase = rb * 256, colBase = cb * 256;
    int kt0 = ks * 64, ktN = kt0 + 64;          // 64 BK=32 steps = K-chunk 2048

    int wr = wid >> 2, wc = wid & 3;            // 2 x 4 waves; wave tile 128 x 64
    int fr = lane & 15, fq = lane >> 4;

    // staging: thread t handles chunk(16B) c0 of row row0 and row0+128 (same swizzle: (row+128)&3 == row&3)
    int row0 = t >> 2, c0 = t & 3;
    int sw0 = (c0 ^ (row0 & 3)) << 3;           // swizzled element offset within BK row
    const ushort_t* aSrc0 = adj16 + (size_t)(rowBase + row0) * NN + sw0;
    const ushort_t* aSrc1 = adj16 + (size_t)(rowBase + row0 + 128) * NN + sw0;
    const ushort_t* bSrc0 = yt + (size_t)(colBase + row0) * NN + sw0;
    const ushort_t* bSrc1 = yt + (size_t)(colBase + row0 + 128) * NN + sw0;

    auto stage = [&](int buf, int kt) {
        int ko = kt * 32;
        gload_lds16(aSrc0 + ko, (char*)As[buf] + wid * 1024);
        gload_lds16(aSrc1 + ko, (char*)As[buf] + 8192 + wid * 1024);
        gload_lds16(bSrc0 + ko, (char*)Bs[buf] + wid * 1024);
        gload_lds16(bSrc1 + ko, (char*)Bs[buf] + 8192 + wid * 1024);
    };

    f32x4 acc[8][4] = {};
    int sws = (fq ^ (fr & 3)) << 4;             // swizzled 16B-chunk byte offset for frag reads

    stage(0, kt0);
    __syncthreads();                            // compiler emits vmcnt(0) before barrier
    int cur = 0;
    for (int kt = kt0; kt < ktN; ++kt) {
        if (kt + 1 < ktN) stage(cur ^ 1, kt + 1);   // loads fly under the MFMA cluster below
        const char* Ab = (const char*)As[cur];
        const char* Bb = (const char*)Bs[cur];
        short8 af[8], bfr[4];
#pragma unroll
        for (int m = 0; m < 8; ++m) {
            int row = wr * 128 + m * 16 + fr;       // row&3 == fr&3
            af[m] = *(const short8*)(Ab + row * 64 + sws);
        }
#pragma unroll
        for (int n = 0; n < 4; ++n) {
            int col = wc * 64 + n * 16 + fr;
            bfr[n] = *(const short8*)(Bb + col * 64 + sws);
        }
        __builtin_amdgcn_s_setprio(1);
#pragma unroll
        for (int m = 0; m < 8; ++m)
#pragma unroll
            for (int n = 0; n < 4; ++n)
                acc[m][n] = __builtin_amdgcn_mfma_f32_16x16x32_bf16(af[m], bfr[n], acc[m][n], 0, 0, 0);
        __builtin_amdgcn_s_setprio(0);
        __syncthreads();                        // drains staged loads (vmcnt 0) + retires reads
        cur ^= 1;
    }

#pragma unroll
    for (int m = 0; m < 8; ++m) {
#pragma unroll
        for (int j = 0; j < 4; ++j) {
            int gr = rowBase + wr * 128 + m * 16 + fq * 4 + j;
            float* dst = &part[((size_t)ks * NN + gr) * CC];
#pragma unroll
            for (int n = 0; n < 4; ++n) {
                int gc = colBase + wc * 64 + n * 16 + fr;
                dst[gc] = acc[m][n][j];
            }
        }
    }
}

// ---------------- Kernel 3 (fallback): f32 A, in-kernel convert, 128^2 tile ----------------
template <int MODE>
__global__ __launch_bounds__(256, 4) void k_gemm1(const float* __restrict__ adj,
                                                  const ushort_t* __restrict__ yt,
                                                  const float* __restrict__ ds,
                                                  const float* __restrict__ x,
                                                  ushort_t* __restrict__ mm1,
                                                  float* __restrict__ part) {
    __shared__ __align__(16) ushort_t As[128 * 64];
    __shared__ __align__(16) ushort_t Bs[128 * 64];

    int t = threadIdx.x;
    int wid = t >> 6, lane = t & 63;

    int rowBase, colBase, kt0, ktN, ks;
    if (MODE == 0) {
        int bid = blockIdx.x;
        bid = (bid & 7) * 32 + (bid >> 3);
        colBase = (bid & 3) * 128;
        rowBase = (bid >> 2) * 128;
        kt0 = 0; ktN = NN / 64; ks = 0;
    } else {
        int gid = blockIdx.x;
        int xcd = gid & 7, slot = gid >> 3;
        int cb = slot & 3;
        int g = (slot >> 2) * 8 + xcd;
        int rb = g & 63; ks = g >> 6;
        rowBase = rb * 128; colBase = cb * 128;
        kt0 = ks * (NN / 64 / 4); ktN = kt0 + NN / 64 / 4;
    }

    int ar = t >> 4;
    int ac4 = t & 15;
    const float* aptr = adj + (size_t)(rowBase + ar) * NN + ac4 * 4;
    int brow0 = t >> 3;
    int bs = t & 7;

    float4 areg[8];

    auto loadA = [&](int kt) {
        const float* p = aptr + kt * 64;
#pragma unroll
        for (int i = 0; i < 8; ++i)
            areg[i] = *(const float4*)(p + (size_t)i * 16 * NN);
    };
    auto writeA = [&]() {
#pragma unroll
        for (int i = 0; i < 8; ++i) {
            int row = i * 16 + ar;
            ushort4 u;
            u.x = f2bf(areg[i].x); u.y = f2bf(areg[i].y);
            u.z = f2bf(areg[i].z); u.w = f2bf(areg[i].w);
            *(ushort4*)((char*)As + row * 128 + ((ac4 * 8) ^ ((row & 7) << 4))) = u;
        }
    };
    auto stageB = [&](int kt) {
#pragma unroll
        for (int j = 0; j < 4; ++j) {
            int row = j * 32 + brow0;
            gload_lds16((const char*)(yt + (size_t)(colBase + row) * NN + kt * 64 +
                                      ((bs ^ (row & 7)) << 3)),
                        (char*)Bs + j * 4096 + wid * 1024);
        }
    };

    f32x4 acc[4][4] = {};
    int wr = wid >> 1, wc = wid & 1;
    int fr = lane & 15, fq = lane >> 4;

    loadA(kt0);
    for (int kt = kt0; kt < ktN; ++kt) {
        writeA();
        stageB(kt);
        __syncthreads();
        if (kt + 1 < ktN) loadA(kt + 1);
#pragma unroll
        for (int ks2 = 0; ks2 < 2; ++ks2) {
            short8 af[4], bf[4];
#pragma unroll
            for (int m = 0; m < 4; ++m) {
                int row = wr * 64 + m * 16 + fr;
                af[m] = *(const short8*)((const char*)As + row * 128 +
                                         ((ks2 * 64 + fq * 16) ^ ((row & 7) << 4)));
            }
#pragma unroll
            for (int n = 0; n < 4; ++n) {
                int col = wc * 64 + n * 16 + fr;
                bf[n] = *(const short8*)((const char*)Bs + col * 128 +
                                         ((ks2 * 64 + fq * 16) ^ ((col & 7) << 4)));
            }
#pragma unroll
            for (int m = 0; m < 4; ++m)
#pragma unroll
                for (int n = 0; n < 4; ++n)
                    acc[m][n] = __builtin_amdgcn_mfma_f32_16x16x32_bf16(af[m], bf[n], acc[m][n], 0, 0, 0);
        }
        __syncthreads();
    }

#pragma unroll
    for (int m = 0; m < 4; ++m) {
#pragma unroll
        for (int j = 0; j < 4; ++j) {
            int gr = rowBase + wr * 64 + m * 16 + fq * 4 + j;
            float dsr = (MODE == 0) ? ds[gr] : 0.f;
#pragma unroll
            for (int n = 0; n < 4; ++n) {
                int gc = colBase + wc * 64 + n * 16 + fr;
                float p = acc[m][n][j];
                if (MODE == 0) {
                    float v = dsr * (p + dsr * x[(size_t)gr * CC + gc]);
                    mm1[(size_t)gr * CC + gc] = f2bf(v);
                } else {
                    part[((size_t)ks * NN + gr) * CC + gc] = p;
                }
            }
        }
    }
}

// ---------------- Kernel 3b: mm1 = bf16( ds*(sum partials + ds*x) ) ----------------
__global__ __launch_bounds__(256) void k_finish(const float* __restrict__ part,
                                                const float* __restrict__ ds,
                                                const float* __restrict__ x,
                                                ushort_t* __restrict__ mm1,
                                                int nsplit) {
    size_t i = (size_t)blockIdx.x * 256 + threadIdx.x;
    const f32x4* p = (const f32x4*)part;
    const size_t stride = (size_t)NN * CC / 4;
    f32x4 s = p[i];
    for (int k = 1; k < nsplit; ++k) s += p[i + (size_t)k * stride];
    int row = (int)(i >> 7);
    float d = ds[row];
    f32x4 xv = ((const f32x4*)x)[i];
    ushort4 u;
    u.x = f2bf(d * (s[0] + d * xv[0]));
    u.y = f2bf(d * (s[1] + d * xv[1]));
    u.z = f2bf(d * (s[2] + d * xv[2]));
    u.w = f2bf(d * (s[3] + d * xv[3]));
    ((ushort4*)mm1)[i] = u;
}

// ---------------- Kernel 4: out = elu(mm1 @ w)  (f32 out) ----------------
__global__ __launch_bounds__(256, 2) void k_gemm2(const ushort_t* __restrict__ mm1,
                                                  const ushort_t* __restrict__ wt,
                                                  float* __restrict__ out) {
    __shared__ __align__(16) ushort_t As[128 * 64];
    __shared__ __align__(16) ushort_t Bs[128 * 64];

    int t = threadIdx.x;
    int wid = t >> 6, lane = t & 63;
    int bid = blockIdx.x;
    bid = (bid & 7) * 32 + (bid >> 3);
    int cb = bid & 3, rb = bid >> 2;
    int rowBase = rb * 128, colBase = cb * 128;

    int srow0 = t >> 3, ss = t & 7;

    f32x4 acc[4][4] = {};
    int wr = wid >> 1, wc = wid & 1;
    int fr = lane & 15, fq = lane >> 4;

    for (int kt = 0; kt < CC / 64; ++kt) {
#pragma unroll
        for (int j = 0; j < 4; ++j) {
            int row = j * 32 + srow0;
            gload_lds16((const char*)(mm1 + (size_t)(rowBase + row) * CC + kt * 64 +
                                      ((ss ^ (row & 7)) << 3)),
                        (char*)As + j * 4096 + wid * 1024);
            gload_lds16((const char*)(wt + (size_t)(colBase + row) * CC + kt * 64 +
                                      ((ss ^ (row & 7)) << 3)),
                        (char*)Bs + j * 4096 + wid * 1024);
        }
        __syncthreads();
#pragma unroll
        for (int ks = 0; ks < 2; ++ks) {
            short8 af[4], bf[4];
#pragma unroll
            for (int m = 0; m < 4; ++m) {
                int row = wr * 64 + m * 16 + fr;
                af[m] = *(const short8*)((const char*)As + row * 128 +
                                         ((ks * 64 + fq * 16) ^ ((row & 7) << 4)));
            }
#pragma unroll
            for (int n = 0; n < 4; ++n) {
                int col = wc * 64 + n * 16 + fr;
                bf[n] = *(const short8*)((const char*)Bs + col * 128 +
                                         ((ks * 64 + fq * 16) ^ ((col & 7) << 4)));
            }
#pragma unroll
            for (int m = 0; m < 4; ++m)
#pragma unroll
                for (int n = 0; n < 4; ++n)
                    acc[m][n] = __builtin_amdgcn_mfma_f32_16x16x32_bf16(af[m], bf[n], acc[m][n], 0, 0, 0);
        }
        __syncthreads();
    }

#pragma unroll
    for (int m = 0; m < 4; ++m) {
#pragma unroll
        for (int j = 0; j < 4; ++j) {
            int gr = rowBase + wr * 64 + m * 16 + fq * 4 + j;
#pragma unroll
            for (int n = 0; n < 4; ++n) {
                int gc = colBase + wc * 64 + n * 16 + fr;
                float v = acc[m][n][j];
                out[(size_t)gr * CC + gc] = v > 0.f ? v : expm1f(v);
            }
        }
    }
}

extern "C" void kernel_launch(void* const* d_in, const int* in_sizes, int n_in,
                              void* d_out, int out_size, void* d_ws, size_t ws_size,
                              hipStream_t stream) {
    const float* x   = (const float*)d_in[0];   // [8192][512]
    const float* adj = (const float*)d_in[1];   // [8192][8192]
    const float* w   = (const float*)d_in[2];   // [512][512]
    float* out = (float*)d_out;                 // [8192][512]

    char* ws = (char*)d_ws;
    size_t off = 0;
    float*    ds  = (float*)(ws + off);  off += 32u << 10;              // 32 KB
    ushort_t* yt  = (ushort_t*)(ws + off);  off += 8u << 20;            // 8 MB [512][8192]
    ushort_t* wt  = (ushort_t*)(ws + off);  off += 512u << 10;          // 512 KB
    ushort_t* mm1 = (ushort_t*)(ws + off);  off += 8u << 20;            // 8 MB [8192][512]
    float*    part = (float*)(ws + off);                                 // split-K partials
    const size_t partBytes = 4 * (size_t)NN * CC * 4;                    // 64 MB
    ushort_t* adj16 = (ushort_t*)(ws + off + partBytes);                 // 128 MB
    const size_t adjBytes = (size_t)NN * NN * 2;

    if (ws_size >= off + partBytes + adjBytes) {
        k_rowsum_cvt<<<NN, 256, 0, stream>>>(adj, ds, adj16);            // ds + adj16
        k_transpose<<<dim3(NN / 64, CC / 64), 256, 0, stream>>>(x, yt, ds, NN, CC);
        k_transpose<<<dim3(CC / 64, CC / 64), 256, 0, stream>>>(w, wt, nullptr, CC, CC);
        k_gemm1c<<<256, 512, 0, stream>>>(adj16, yt, part);
        k_finish<<<NN * CC / 4 / 256, 256, 0, stream>>>(part, ds, x, mm1, 4);
    } else if (ws_size >= off + partBytes) {
        k_rowsum<<<NN, 256, 0, stream>>>(adj, ds);
        k_transpose<<<dim3(NN / 64, CC / 64), 256, 0, stream>>>(x, yt, ds, NN, CC);
        k_transpose<<<dim3(CC / 64, CC / 64), 256, 0, stream>>>(w, wt, nullptr, CC, CC);
        k_gemm1<1><<<1024, 256, 0, stream>>>(adj, yt, ds, x, mm1, part);
        k_finish<<<NN * CC / 4 / 256, 256, 0, stream>>>(part, ds, x, mm1, 4);
    } else {
        k_rowsum<<<NN, 256, 0, stream>>>(adj, ds);
        k_transpose<<<dim3(NN / 64, CC / 64), 256, 0, stream>>>(x, yt, ds, NN, CC);
        k_transpose<<<dim3(CC / 64, CC / 64), 256, 0, stream>>>(w, wt, nullptr, CC, CC);
        k_gemm1<0><<<256, 256, 0, stream>>>(adj, yt, ds, x, mm1, part);
    }

    k_gemm2<<<256, 256, 0, stream>>>(mm1, wt, out);
}

// Round 5
// 228.487 us; speedup vs baseline: 1.0060x; 1.0060x over previous
//
#include <hip/hip_runtime.h>

#define NN 8192
#define CC 512

typedef __attribute__((ext_vector_type(8))) short short8;
typedef __attribute__((ext_vector_type(4))) float f32x4;
typedef unsigned short ushort_t;

__device__ __forceinline__ unsigned short f2bf(float f) {
    unsigned int u = __float_as_uint(f);
    u += 0x7FFF + ((u >> 16) & 1);
    return (unsigned short)(u >> 16);
}

__device__ __forceinline__ void gload_lds16(const void* g, void* l) {
    __builtin_amdgcn_global_load_lds((const __attribute__((address_space(1))) unsigned int*)g,
                                     (__attribute__((address_space(3))) unsigned int*)l,
                                     16, 0, 0);
}

// ---------------- Kernel 1: ds = rsqrt(rowsum(adj)+1);  adj16 = bf16(adj) (fused) ----------------
__global__ __launch_bounds__(256) void k_rowsum_cvt(const float* __restrict__ adj,
                                                    float* __restrict__ ds,
                                                    ushort_t* __restrict__ adj16) {
    int row = blockIdx.x;
    const float4* p = (const float4*)(adj + (size_t)row * NN);
    ushort4* q = (ushort4*)(adj16 + (size_t)row * NN);
    float s = 0.f;
#pragma unroll
    for (int i = 0; i < 8; ++i) {
        float4 v = p[threadIdx.x + i * 256];
        s += (v.x + v.y) + (v.z + v.w);
        ushort4 u;
        u.x = f2bf(v.x); u.y = f2bf(v.y); u.z = f2bf(v.z); u.w = f2bf(v.w);
        q[threadIdx.x + i * 256] = u;
    }
#pragma unroll
    for (int off = 32; off > 0; off >>= 1) s += __shfl_down(s, off, 64);
    __shared__ float partial[4];
    if ((threadIdx.x & 63) == 0) partial[threadIdx.x >> 6] = s;
    __syncthreads();
    if (threadIdx.x == 0) {
        float deg = ((partial[0] + partial[1]) + (partial[2] + partial[3])) + 1.0f;
        ds[row] = rsqrtf(deg);
    }
}

// plain rowsum (fallback path)
__global__ __launch_bounds__(256) void k_rowsum(const float* __restrict__ adj,
                                                float* __restrict__ ds) {
    int row = blockIdx.x;
    const float4* p = (const float4*)(adj + (size_t)row * NN);
    float s = 0.f;
#pragma unroll
    for (int i = 0; i < 8; ++i) {
        float4 v = p[threadIdx.x + i * 256];
        s += (v.x + v.y) + (v.z + v.w);
    }
#pragma unroll
    for (int off = 32; off > 0; off >>= 1) s += __shfl_down(s, off, 64);
    __shared__ float partial[4];
    if ((threadIdx.x & 63) == 0) partial[threadIdx.x >> 6] = s;
    __syncthreads();
    if (threadIdx.x == 0) {
        float deg = ((partial[0] + partial[1]) + (partial[2] + partial[3])) + 1.0f;
        ds[row] = rsqrtf(deg);
    }
}

// ---------------- Kernel 2: out[c][r] = bf16( in[r][c] * (scale ? scale[r] : 1) ) ----------------
__global__ __launch_bounds__(256) void k_transpose(const float* __restrict__ in,
                                                   ushort_t* __restrict__ out,
                                                   const float* __restrict__ scale,
                                                   int R, int C) {
    __shared__ float tile[64][65];
    int r0 = blockIdx.x * 64, c0 = blockIdx.y * 64;
    int t = threadIdx.x;
    int cl = t & 63;
    int rl0 = t >> 6;
#pragma unroll
    for (int i = 0; i < 16; ++i) {
        int r = rl0 + i * 4;
        float v = in[(size_t)(r0 + r) * C + c0 + cl];
        float sc = scale ? scale[r0 + r] : 1.0f;
        tile[r][cl] = v * sc;
    }
    __syncthreads();
#pragma unroll
    for (int i = 0; i < 16; ++i) {
        int c = rl0 + i * 4;
        int r = cl;
        out[(size_t)(c0 + c) * R + r0 + r] = f2bf(tile[r][c]);
    }
}

// ---------------- Kernel 3 (primary): 256x256 tile, BK=32, 4-deep pipeline, counted vmcnt ----------------
// adj16 bf16 [NN][NN]; yt bf16 [CC][NN]; part f32 [4][NN][CC]
// T3+T4: raw s_barrier (no vmcnt drain) + vmcnt(12) (= 4 loads/stage x 3 tiles in flight).
// LDS swizzle: 16B-chunk c stored at c ^ ((row>>1)&3)  (conflict-free for 64B rows; involution).
__global__ __launch_bounds__(512, 2) void k_gemm1c(const ushort_t* __restrict__ adj16,
                                                   const ushort_t* __restrict__ yt,
                                                   float* __restrict__ part) {
    __shared__ __align__(16) ushort_t As[4][256 * 32];   // 4 x 16 KB
    __shared__ __align__(16) ushort_t Bs[4][256 * 32];   // 4 x 16 KB

    int t = threadIdx.x;
    int wid = t >> 6, lane = t & 63;

    // grid 256 = xcd(8) x slot(32); cb-pair sharing an A-chunk is adjacent on one XCD
    int gid = blockIdx.x;
    int xcd = gid & 7, slot = gid >> 3;
    int cb = slot & 1;
    int u = (slot >> 1) + 16 * xcd;             // [0,128) = (rb,ks), bijective
    int rb = u & 31, ks = u >> 5;
    int rowBase = rb * 256, colBase = cb * 256;
    int kt0 = ks * 64;                          // 64 steps of BK=32 = K-chunk 2048

    int wr = wid >> 2, wc = wid & 3;            // 2 x 4 waves; wave tile 128 x 64
    int fr = lane & 15, fq = lane >> 4;

    // staging: thread t -> row0 = t>>2 (of 128), chunk c0 = t&3; rows row0 and row0+128
    int row0 = t >> 2, c0 = t & 3;
    int sw0 = (c0 ^ ((row0 >> 1) & 3)) << 3;    // pre-swizzled element offset ((row+128)>>1)&3 is same
    const ushort_t* aSrc0 = adj16 + (size_t)(rowBase + row0) * NN + sw0;
    const ushort_t* aSrc1 = adj16 + (size_t)(rowBase + row0 + 128) * NN + sw0;
    const ushort_t* bSrc0 = yt + (size_t)(colBase + row0) * NN + sw0;
    const ushort_t* bSrc1 = yt + (size_t)(colBase + row0 + 128) * NN + sw0;

    auto stage = [&](int buf, int kt) {         // kt absolute
        int ko = kt * 32;
        gload_lds16(aSrc0 + ko, (char*)As[buf] + wid * 1024);
        gload_lds16(aSrc1 + ko, (char*)As[buf] + 8192 + wid * 1024);
        gload_lds16(bSrc0 + ko, (char*)Bs[buf] + wid * 1024);
        gload_lds16(bSrc1 + ko, (char*)Bs[buf] + 8192 + wid * 1024);
    };

    f32x4 acc[8][4] = {};
    int sws = (fq ^ ((fr >> 1) & 3)) << 4;      // swizzled 16B-chunk byte offset for frag reads

    // prologue: tiles 0,1,2 -> bufs 0,1,2
    stage(0, kt0 + 0);
    stage(1, kt0 + 1);
    stage(2, kt0 + 2);

    for (int j = 0; j < 64; ++j) {
        // (a) stage tile j+3 into buf (j+3)&3 (dummy wrap for last 3 iters -> dead buffers)
        stage((j + 3) & 3, kt0 + ((j + 3) & 63));
        // (b) 12 outstanding = tiles j+1..j+3  =>  my 4 loads for tile j have landed
        asm volatile("s_waitcnt vmcnt(12)" ::: "memory");
        __builtin_amdgcn_sched_barrier(0);
        // (c) all waves passed (b) => tile j fully in LDS
        __builtin_amdgcn_s_barrier();
        __builtin_amdgcn_sched_barrier(0);

        const char* Ab = (const char*)As[j & 3];
        const char* Bb = (const char*)Bs[j & 3];
        short8 af[8], bfr[4];
#pragma unroll
        for (int m = 0; m < 8; ++m)
            af[m] = *(const short8*)(Ab + (wr * 128 + m * 16 + fr) * 64 + sws);
#pragma unroll
        for (int n = 0; n < 4; ++n)
            bfr[n] = *(const short8*)(Bb + (wc * 64 + n * 16 + fr) * 64 + sws);

        __builtin_amdgcn_s_setprio(1);
#pragma unroll
        for (int m = 0; m < 8; ++m)
#pragma unroll
            for (int n = 0; n < 4; ++n)
                acc[m][n] = __builtin_amdgcn_mfma_f32_16x16x32_bf16(af[m], bfr[n], acc[m][n], 0, 0, 0);
        __builtin_amdgcn_s_setprio(0);
        __builtin_amdgcn_sched_barrier(0);
        // (e) all waves done reading buf j  =>  iter j+1 may overwrite it
        __builtin_amdgcn_s_barrier();
        __builtin_amdgcn_sched_barrier(0);
    }

#pragma unroll
    for (int m = 0; m < 8; ++m) {
#pragma unroll
        for (int j = 0; j < 4; ++j) {
            int gr = rowBase + wr * 128 + m * 16 + fq * 4 + j;
            float* dst = &part[((size_t)ks * NN + gr) * CC];
#pragma unroll
            for (int n = 0; n < 4; ++n) {
                int gc = colBase + wc * 64 + n * 16 + fr;
                dst[gc] = acc[m][n][j];
            }
        }
    }
}

// ---------------- Kernel 3 (fallback): f32 A, in-kernel convert, 128^2 tile ----------------
template <int MODE>
__global__ __launch_bounds__(256, 4) void k_gemm1(const float* __restrict__ adj,
                                                  const ushort_t* __restrict__ yt,
                                                  const float* __restrict__ ds,
                                                  const float* __restrict__ x,
                                                  ushort_t* __restrict__ mm1,
                                                  float* __restrict__ part) {
    __shared__ __align__(16) ushort_t As[128 * 64];
    __shared__ __align__(16) ushort_t Bs[128 * 64];

    int t = threadIdx.x;
    int wid = t >> 6, lane = t & 63;

    int rowBase, colBase, kt0, ktN, ks;
    if (MODE == 0) {
        int bid = blockIdx.x;
        bid = (bid & 7) * 32 + (bid >> 3);
        colBase = (bid & 3) * 128;
        rowBase = (bid >> 2) * 128;
        kt0 = 0; ktN = NN / 64; ks = 0;
    } else {
        int gid = blockIdx.x;
        int xcd = gid & 7, slot = gid >> 3;
        int cb = slot & 3;
        int g = (slot >> 2) * 8 + xcd;
        int rb = g & 63; ks = g >> 6;
        rowBase = rb * 128; colBase = cb * 128;
        kt0 = ks * (NN / 64 / 4); ktN = kt0 + NN / 64 / 4;
    }

    int ar = t >> 4;
    int ac4 = t & 15;
    const float* aptr = adj + (size_t)(rowBase + ar) * NN + ac4 * 4;
    int brow0 = t >> 3;
    int bs = t & 7;

    float4 areg[8];

    auto loadA = [&](int kt) {
        const float* p = aptr + kt * 64;
#pragma unroll
        for (int i = 0; i < 8; ++i)
            areg[i] = *(const float4*)(p + (size_t)i * 16 * NN);
    };
    auto writeA = [&]() {
#pragma unroll
        for (int i = 0; i < 8; ++i) {
            int row = i * 16 + ar;
            ushort4 u;
            u.x = f2bf(areg[i].x); u.y = f2bf(areg[i].y);
            u.z = f2bf(areg[i].z); u.w = f2bf(areg[i].w);
            *(ushort4*)((char*)As + row * 128 + ((ac4 * 8) ^ ((row & 7) << 4))) = u;
        }
    };
    auto stageB = [&](int kt) {
#pragma unroll
        for (int j = 0; j < 4; ++j) {
            int row = j * 32 + brow0;
            gload_lds16((const char*)(yt + (size_t)(colBase + row) * NN + kt * 64 +
                                      ((bs ^ (row & 7)) << 3)),
                        (char*)Bs + j * 4096 + wid * 1024);
        }
    };

    f32x4 acc[4][4] = {};
    int wr = wid >> 1, wc = wid & 1;
    int fr = lane & 15, fq = lane >> 4;

    loadA(kt0);
    for (int kt = kt0; kt < ktN; ++kt) {
        writeA();
        stageB(kt);
        __syncthreads();
        if (kt + 1 < ktN) loadA(kt + 1);
#pragma unroll
        for (int ks2 = 0; ks2 < 2; ++ks2) {
            short8 af[4], bf[4];
#pragma unroll
            for (int m = 0; m < 4; ++m) {
                int row = wr * 64 + m * 16 + fr;
                af[m] = *(const short8*)((const char*)As + row * 128 +
                                         ((ks2 * 64 + fq * 16) ^ ((row & 7) << 4)));
            }
#pragma unroll
            for (int n = 0; n < 4; ++n) {
                int col = wc * 64 + n * 16 + fr;
                bf[n] = *(const short8*)((const char*)Bs + col * 128 +
                                         ((ks2 * 64 + fq * 16) ^ ((col & 7) << 4)));
            }
#pragma unroll
            for (int m = 0; m < 4; ++m)
#pragma unroll
                for (int n = 0; n < 4; ++n)
                    acc[m][n] = __builtin_amdgcn_mfma_f32_16x16x32_bf16(af[m], bf[n], acc[m][n], 0, 0, 0);
        }
        __syncthreads();
    }

#pragma unroll
    for (int m = 0; m < 4; ++m) {
#pragma unroll
        for (int j = 0; j < 4; ++j) {
            int gr = rowBase + wr * 64 + m * 16 + fq * 4 + j;
            float dsr = (MODE == 0) ? ds[gr] : 0.f;
#pragma unroll
            for (int n = 0; n < 4; ++n) {
                int gc = colBase + wc * 64 + n * 16 + fr;
                float p = acc[m][n][j];
                if (MODE == 0) {
                    float v = dsr * (p + dsr * x[(size_t)gr * CC + gc]);
                    mm1[(size_t)gr * CC + gc] = f2bf(v);
                } else {
                    part[((size_t)ks * NN + gr) * CC + gc] = p;
                }
            }
        }
    }
}

// ---------------- Kernel 3b: mm1 = bf16( ds*(sum partials + ds*x) ) ----------------
__global__ __launch_bounds__(256) void k_finish(const float* __restrict__ part,
                                                const float* __restrict__ ds,
                                                const float* __restrict__ x,
                                                ushort_t* __restrict__ mm1,
                                                int nsplit) {
    size_t i = (size_t)blockIdx.x * 256 + threadIdx.x;
    const f32x4* p = (const f32x4*)part;
    const size_t stride = (size_t)NN * CC / 4;
    f32x4 s = p[i];
    for (int k = 1; k < nsplit; ++k) s += p[i + (size_t)k * stride];
    int row = (int)(i >> 7);
    float d = ds[row];
    f32x4 xv = ((const f32x4*)x)[i];
    ushort4 u;
    u.x = f2bf(d * (s[0] + d * xv[0]));
    u.y = f2bf(d * (s[1] + d * xv[1]));
    u.z = f2bf(d * (s[2] + d * xv[2]));
    u.w = f2bf(d * (s[3] + d * xv[3]));
    ((ushort4*)mm1)[i] = u;
}

// ---------------- Kernel 4: out = elu(mm1 @ w)  (f32 out) ----------------
__global__ __launch_bounds__(256, 2) void k_gemm2(const ushort_t* __restrict__ mm1,
                                                  const ushort_t* __restrict__ wt,
                                                  float* __restrict__ out) {
    __shared__ __align__(16) ushort_t As[128 * 64];
    __shared__ __align__(16) ushort_t Bs[128 * 64];

    int t = threadIdx.x;
    int wid = t >> 6, lane = t & 63;
    int bid = blockIdx.x;
    bid = (bid & 7) * 32 + (bid >> 3);
    int cb = bid & 3, rb = bid >> 2;
    int rowBase = rb * 128, colBase = cb * 128;

    int srow0 = t >> 3, ss = t & 7;

    f32x4 acc[4][4] = {};
    int wr = wid >> 1, wc = wid & 1;
    int fr = lane & 15, fq = lane >> 4;

    for (int kt = 0; kt < CC / 64; ++kt) {
#pragma unroll
        for (int j = 0; j < 4; ++j) {
            int row = j * 32 + srow0;
            gload_lds16((const char*)(mm1 + (size_t)(rowBase + row) * CC + kt * 64 +
                                      ((ss ^ (row & 7)) << 3)),
                        (char*)As + j * 4096 + wid * 1024);
            gload_lds16((const char*)(wt + (size_t)(colBase + row) * CC + kt * 64 +
                                      ((ss ^ (row & 7)) << 3)),
                        (char*)Bs + j * 4096 + wid * 1024);
        }
        __syncthreads();
#pragma unroll
        for (int ks = 0; ks < 2; ++ks) {
            short8 af[4], bf[4];
#pragma unroll
            for (int m = 0; m < 4; ++m) {
                int row = wr * 64 + m * 16 + fr;
                af[m] = *(const short8*)((const char*)As + row * 128 +
                                         ((ks * 64 + fq * 16) ^ ((row & 7) << 4)));
            }
#pragma unroll
            for (int n = 0; n < 4; ++n) {
                int col = wc * 64 + n * 16 + fr;
                bf[n] = *(const short8*)((const char*)Bs + col * 128 +
                                         ((ks * 64 + fq * 16) ^ ((col & 7) << 4)));
            }
#pragma unroll
            for (int m = 0; m < 4; ++m)
#pragma unroll
                for (int n = 0; n < 4; ++n)
                    acc[m][n] = __builtin_amdgcn_mfma_f32_16x16x32_bf16(af[m], bf[n], acc[m][n], 0, 0, 0);
        }
        __syncthreads();
    }

#pragma unroll
    for (int m = 0; m < 4; ++m) {
#pragma unroll
        for (int j = 0; j < 4; ++j) {
            int gr = rowBase + wr * 64 + m * 16 + fq * 4 + j;
#pragma unroll
            for (int n = 0; n < 4; ++n) {
                int gc = colBase + wc * 64 + n * 16 + fr;
                float v = acc[m][n][j];
                out[(size_t)gr * CC + gc] = v > 0.f ? v : expm1f(v);
            }
        }
    }
}

extern "C" void kernel_launch(void* const* d_in, const int* in_sizes, int n_in,
                              void* d_out, int out_size, void* d_ws, size_t ws_size,
                              hipStream_t stream) {
    const float* x   = (const float*)d_in[0];   // [8192][512]
    const float* adj = (const float*)d_in[1];   // [8192][8192]
    const float* w   = (const float*)d_in[2];   // [512][512]
    float* out = (float*)d_out;                 // [8192][512]

    char* ws = (char*)d_ws;
    size_t off = 0;
    float*    ds  = (float*)(ws + off);  off += 32u << 10;              // 32 KB
    ushort_t* yt  = (ushort_t*)(ws + off);  off += 8u << 20;            // 8 MB [512][8192]
    ushort_t* wt  = (ushort_t*)(ws + off);  off += 512u << 10;          // 512 KB
    ushort_t* mm1 = (ushort_t*)(ws + off);  off += 8u << 20;            // 8 MB [8192][512]
    float*    part = (float*)(ws + off);                                 // split-K partials
    const size_t partBytes = 4 * (size_t)NN * CC * 4;                    // 64 MB
    ushort_t* adj16 = (ushort_t*)(ws + off + partBytes);                 // 128 MB
    const size_t adjBytes = (size_t)NN * NN * 2;

    if (ws_size >= off + partBytes + adjBytes) {
        k_rowsum_cvt<<<NN, 256, 0, stream>>>(adj, ds, adj16);            // ds + adj16
        k_transpose<<<dim3(NN / 64, CC / 64), 256, 0, stream>>>(x, yt, ds, NN, CC);
        k_transpose<<<dim3(CC / 64, CC / 64), 256, 0, stream>>>(w, wt, nullptr, CC, CC);
        k_gemm1c<<<256, 512, 0, stream>>>(adj16, yt, part);
        k_finish<<<NN * CC / 4 / 256, 256, 0, stream>>>(part, ds, x, mm1, 4);
    } else if (ws_size >= off + partBytes) {
        k_rowsum<<<NN, 256, 0, stream>>>(adj, ds);
        k_transpose<<<dim3(NN / 64, CC / 64), 256, 0, stream>>>(x, yt, ds, NN, CC);
        k_transpose<<<dim3(CC / 64, CC / 64), 256, 0, stream>>>(w, wt, nullptr, CC, CC);
        k_gemm1<1><<<1024, 256, 0, stream>>>(adj, yt, ds, x, mm1, part);
        k_finish<<<NN * CC / 4 / 256, 256, 0, stream>>>(part, ds, x, mm1, 4);
    } else {
        k_rowsum<<<NN, 256, 0, stream>>>(adj, ds);
        k_transpose<<<dim3(NN / 64, CC / 64), 256, 0, stream>>>(x, yt, ds, NN, CC);
        k_transpose<<<dim3(CC / 64, CC / 64), 256, 0, stream>>>(w, wt, nullptr, CC, CC);
        k_gemm1<0><<<256, 256, 0, stream>>>(adj, yt, ds, x, mm1, part);
    }

    k_gemm2<<<256, 256, 0, stream>>>(mm1, wt, out);
}

// Round 6
// 214.739 us; speedup vs baseline: 1.0704x; 1.0640x over previous
//
#include <hip/hip_runtime.h>

#define NN 8192
#define CC 512

typedef __attribute__((ext_vector_type(8))) short short8;
typedef __attribute__((ext_vector_type(4))) float f32x4;
typedef unsigned short ushort_t;

__device__ __forceinline__ unsigned short f2bf(float f) {
    unsigned int u = __float_as_uint(f);
    u += 0x7FFF + ((u >> 16) & 1);
    return (unsigned short)(u >> 16);
}
__device__ __forceinline__ float bf2f(unsigned short u) {
    return __uint_as_float(((unsigned int)u) << 16);
}

__device__ __forceinline__ void gload_lds16(const void* g, void* l) {
    __builtin_amdgcn_global_load_lds((const __attribute__((address_space(1))) unsigned int*)g,
                                     (__attribute__((address_space(3))) unsigned int*)l,
                                     16, 0, 0);
}

// ---------------- Kernel 1: ds = rsqrt(rowsum(adj)+1);  adj16 = bf16(adj) (fused) ----------------
__global__ __launch_bounds__(256) void k_rowsum_cvt(const float* __restrict__ adj,
                                                    float* __restrict__ ds,
                                                    ushort_t* __restrict__ adj16) {
    int row = blockIdx.x;
    const float4* p = (const float4*)(adj + (size_t)row * NN);
    ushort4* q = (ushort4*)(adj16 + (size_t)row * NN);
    float s = 0.f;
#pragma unroll
    for (int i = 0; i < 8; ++i) {
        float4 v = p[threadIdx.x + i * 256];
        s += (v.x + v.y) + (v.z + v.w);
        ushort4 u;
        u.x = f2bf(v.x); u.y = f2bf(v.y); u.z = f2bf(v.z); u.w = f2bf(v.w);
        q[threadIdx.x + i * 256] = u;
    }
#pragma unroll
    for (int off = 32; off > 0; off >>= 1) s += __shfl_down(s, off, 64);
    __shared__ float partial[4];
    if ((threadIdx.x & 63) == 0) partial[threadIdx.x >> 6] = s;
    __syncthreads();
    if (threadIdx.x == 0) {
        float deg = ((partial[0] + partial[1]) + (partial[2] + partial[3])) + 1.0f;
        ds[row] = rsqrtf(deg);
    }
}

// plain rowsum (fallback path)
__global__ __launch_bounds__(256) void k_rowsum(const float* __restrict__ adj,
                                                float* __restrict__ ds) {
    int row = blockIdx.x;
    const float4* p = (const float4*)(adj + (size_t)row * NN);
    float s = 0.f;
#pragma unroll
    for (int i = 0; i < 8; ++i) {
        float4 v = p[threadIdx.x + i * 256];
        s += (v.x + v.y) + (v.z + v.w);
    }
#pragma unroll
    for (int off = 32; off > 0; off >>= 1) s += __shfl_down(s, off, 64);
    __shared__ float partial[4];
    if ((threadIdx.x & 63) == 0) partial[threadIdx.x >> 6] = s;
    __syncthreads();
    if (threadIdx.x == 0) {
        float deg = ((partial[0] + partial[1]) + (partial[2] + partial[3])) + 1.0f;
        ds[row] = rsqrtf(deg);
    }
}

// ---------------- elementwise f32 -> bf16 ----------------
__global__ __launch_bounds__(256) void k_cvt(const float* __restrict__ in,
                                             ushort_t* __restrict__ out) {
    size_t i = (size_t)blockIdx.x * 256 + threadIdx.x;
    float4 v = ((const float4*)in)[i];
    ushort4 u;
    u.x = f2bf(v.x); u.y = f2bf(v.y); u.z = f2bf(v.z); u.w = f2bf(v.w);
    ((ushort4*)out)[i] = u;
}

// ---------------- Kernel 2: out[c][r] = bf16( in[r][c] * (scale ? scale[r] : 1) ) ----------------
__global__ __launch_bounds__(256) void k_transpose(const float* __restrict__ in,
                                                   ushort_t* __restrict__ out,
                                                   const float* __restrict__ scale,
                                                   int R, int C) {
    __shared__ float tile[64][65];
    int r0 = blockIdx.x * 64, c0 = blockIdx.y * 64;
    int t = threadIdx.x;
    int cl = t & 63;
    int rl0 = t >> 6;
#pragma unroll
    for (int i = 0; i < 16; ++i) {
        int r = rl0 + i * 4;
        float v = in[(size_t)(r0 + r) * C + c0 + cl];
        float sc = scale ? scale[r0 + r] : 1.0f;
        tile[r][cl] = v * sc;
    }
    __syncthreads();
#pragma unroll
    for (int i = 0; i < 16; ++i) {
        int c = rl0 + i * 4;
        int r = cl;
        out[(size_t)(c0 + c) * R + r0 + r] = f2bf(tile[r][c]);
    }
}

// ---------------- small GEMM (128^2 tile, 2-phase): out = [elu](A @ Bt) ----------------
// A bf16 [NN][CC]; Bt bf16 [CC][CC] (col-major B); out f32 [NN][CC]
template <bool ELU>
__global__ __launch_bounds__(256, 2) void k_gemm2t(const ushort_t* __restrict__ A,
                                                   const ushort_t* __restrict__ Bt,
                                                   float* __restrict__ out) {
    __shared__ __align__(16) ushort_t As[128 * 64];
    __shared__ __align__(16) ushort_t Bs[128 * 64];

    int t = threadIdx.x;
    int wid = t >> 6, lane = t & 63;
    int bid = blockIdx.x;
    bid = (bid & 7) * 32 + (bid >> 3);
    int cb = bid & 3, rb = bid >> 2;
    int rowBase = rb * 128, colBase = cb * 128;

    int srow0 = t >> 3, ss = t & 7;

    f32x4 acc[4][4] = {};
    int wr = wid >> 1, wc = wid & 1;
    int fr = lane & 15, fq = lane >> 4;

    for (int kt = 0; kt < CC / 64; ++kt) {
#pragma unroll
        for (int j = 0; j < 4; ++j) {
            int row = j * 32 + srow0;
            gload_lds16((const char*)(A + (size_t)(rowBase + row) * CC + kt * 64 +
                                      ((ss ^ (row & 7)) << 3)),
                        (char*)As + j * 4096 + wid * 1024);
            gload_lds16((const char*)(Bt + (size_t)(colBase + row) * CC + kt * 64 +
                                      ((ss ^ (row & 7)) << 3)),
                        (char*)Bs + j * 4096 + wid * 1024);
        }
        __syncthreads();
#pragma unroll
        for (int ks = 0; ks < 2; ++ks) {
            short8 af[4], bf[4];
#pragma unroll
            for (int m = 0; m < 4; ++m) {
                int row = wr * 64 + m * 16 + fr;
                af[m] = *(const short8*)((const char*)As + row * 128 +
                                         ((ks * 64 + fq * 16) ^ ((row & 7) << 4)));
            }
#pragma unroll
            for (int n = 0; n < 4; ++n) {
                int col = wc * 64 + n * 16 + fr;
                bf[n] = *(const short8*)((const char*)Bs + col * 128 +
                                         ((ks * 64 + fq * 16) ^ ((col & 7) << 4)));
            }
#pragma unroll
            for (int m = 0; m < 4; ++m)
#pragma unroll
                for (int n = 0; n < 4; ++n)
                    acc[m][n] = __builtin_amdgcn_mfma_f32_16x16x32_bf16(af[m], bf[n], acc[m][n], 0, 0, 0);
        }
        __syncthreads();
    }

#pragma unroll
    for (int m = 0; m < 4; ++m) {
#pragma unroll
        for (int j = 0; j < 4; ++j) {
            int gr = rowBase + wr * 64 + m * 16 + fq * 4 + j;
#pragma unroll
            for (int n = 0; n < 4; ++n) {
                int gc = colBase + wc * 64 + n * 16 + fr;
                float v = acc[m][n][j];
                out[(size_t)gr * CC + gc] = ELU ? (v > 0.f ? v : expm1f(v)) : v;
            }
        }
    }
}

// ---------------- Kernel 3 (primary): 256^2 tile, K32 sub-tiles, phase-interleaved, counted vmcnt ----------------
// adj16 bf16 [NN][NN]; yt2 bf16 [CC][NN]; part16 bf16 [4][NN][CC]
// dbuf at ITER granularity (iter = 2 K32 tiles): stage buf != read buf -> no WAR race.
// Per phase: {ds-read quadrant} {stage 1 half-pair (2 loads)} {vmcnt(4)} {s_barrier} {16 MFMA} {s_barrier}.
__global__ __launch_bounds__(512, 2) void k_gemm1d(const ushort_t* __restrict__ adj16,
                                                   const ushort_t* __restrict__ yt2,
                                                   ushort_t* __restrict__ part16) {
    __shared__ __align__(16) ushort_t Al[2][2][2][128 * 32];   // [dbuf][tile][half] 8KB each = 64KB
    __shared__ __align__(16) ushort_t Bl[2][2][2][128 * 32];   // 64KB -> 128KB total

    int t = threadIdx.x;
    int wid = t >> 6, lane = t & 63;
    int fr = lane & 15, fq = lane >> 4;

    int gid = blockIdx.x;
    int xcd = gid & 7, slot = gid >> 3;
    int cb = slot & 1;
    int u = (slot >> 1) + 16 * xcd;             // [0,128) bijective
    int rb = u & 31, ks = u >> 5;
    int rowBase = rb * 256, colBase = cb * 256;
    size_t kt0 = (size_t)ks * 2048;

    int wr = wid >> 2, wc = wid & 3;            // wave tile 128x64

    // staging: thread t -> row (t>>2) in [0,128), 16B-chunk (t&3), swizzle chunk ^= (row>>1)&3
    int srow = t >> 2;
    int sw = ((t & 3) ^ ((srow >> 1) & 3)) << 3;
    const ushort_t* aBase = adj16 + (size_t)(rowBase + srow) * NN + sw;
    const ushort_t* bBase = yt2 + (size_t)(colBase + srow) * NN + sw;

    f32x4 acc[8][4] = {};
    int sws = (fq ^ ((fr >> 1) & 3)) << 4;      // swizzled 16B-chunk byte offset for frag reads

    // prologue: stage iter 0 fully, drain once
#pragma unroll
    for (int tt = 0; tt < 2; ++tt)
#pragma unroll
        for (int h = 0; h < 2; ++h) {
            gload_lds16(aBase + (size_t)(h * 128) * NN + kt0 + tt * 32,
                        (char*)Al[0][tt][h] + wid * 1024);
            gload_lds16(bBase + (size_t)(h * 128) * NN + kt0 + tt * 32,
                        (char*)Bl[0][tt][h] + wid * 1024);
        }
    asm volatile("s_waitcnt vmcnt(0)" ::: "memory");
    __syncthreads();

    for (int i = 0; i < 32; ++i) {
        int cur = i & 1, nxt = cur ^ 1;
        size_t Kn = kt0 + (size_t)(((i + 1) & 31) * 64);
#pragma unroll
        for (int tt = 0; tt < 2; ++tt) {
            const char* Ab = (const char*)Al[cur][tt][wr];
            const char* Bb = (const char*)Bl[cur][tt][wc >> 1];
            int bcol0 = (wc & 1) * 64;
            // ---- phase (tt, mh=0): read af0 + bf, stage A halves of next iter tile tt ----
            short8 af0[4], bf[4];
#pragma unroll
            for (int m = 0; m < 4; ++m)
                af0[m] = *(const short8*)(Ab + (m * 16 + fr) * 64 + sws);
#pragma unroll
            for (int n = 0; n < 4; ++n)
                bf[n] = *(const short8*)(Bb + (bcol0 + n * 16 + fr) * 64 + sws);
            gload_lds16(aBase + Kn + tt * 32, (char*)Al[nxt][tt][0] + wid * 1024);
            gload_lds16(aBase + (size_t)128 * NN + Kn + tt * 32, (char*)Al[nxt][tt][1] + wid * 1024);
            asm volatile("s_waitcnt vmcnt(4)" ::: "memory");
            __builtin_amdgcn_sched_barrier(0);
            __builtin_amdgcn_s_barrier();
            __builtin_amdgcn_sched_barrier(0);
            __builtin_amdgcn_s_setprio(1);
#pragma unroll
            for (int m = 0; m < 4; ++m)
#pragma unroll
                for (int n = 0; n < 4; ++n)
                    acc[m][n] = __builtin_amdgcn_mfma_f32_16x16x32_bf16(af0[m], bf[n], acc[m][n], 0, 0, 0);
            __builtin_amdgcn_s_setprio(0);
            __builtin_amdgcn_sched_barrier(0);
            __builtin_amdgcn_s_barrier();
            __builtin_amdgcn_sched_barrier(0);
            // ---- phase (tt, mh=1): read af1, stage B halves of next iter tile tt ----
            short8 af1[4];
#pragma unroll
            for (int m = 0; m < 4; ++m)
                af1[m] = *(const short8*)(Ab + ((64 + m * 16 + fr) * 64) + sws);
            gload_lds16(bBase + Kn + tt * 32, (char*)Bl[nxt][tt][0] + wid * 1024);
            gload_lds16(bBase + (size_t)128 * NN + Kn + tt * 32, (char*)Bl[nxt][tt][1] + wid * 1024);
            asm volatile("s_waitcnt vmcnt(4)" ::: "memory");
            __builtin_amdgcn_sched_barrier(0);
            __builtin_amdgcn_s_barrier();
            __builtin_amdgcn_sched_barrier(0);
            __builtin_amdgcn_s_setprio(1);
#pragma unroll
            for (int m = 0; m < 4; ++m)
#pragma unroll
                for (int n = 0; n < 4; ++n)
                    acc[4 + m][n] = __builtin_amdgcn_mfma_f32_16x16x32_bf16(af1[m], bf[n], acc[4 + m][n], 0, 0, 0);
            __builtin_amdgcn_s_setprio(0);
            __builtin_amdgcn_sched_barrier(0);
            __builtin_amdgcn_s_barrier();
            __builtin_amdgcn_sched_barrier(0);
        }
    }

    // epilogue: bf16 partials
#pragma unroll
    for (int m = 0; m < 8; ++m) {
#pragma unroll
        for (int jj = 0; jj < 4; ++jj) {
            int gr = rowBase + wr * 128 + m * 16 + fq * 4 + jj;
            ushort_t* dst = part16 + ((size_t)ks * NN + gr) * CC + colBase;
#pragma unroll
            for (int n = 0; n < 4; ++n)
                dst[wc * 64 + n * 16 + fr] = f2bf(acc[m][n][jj]);
        }
    }
}

// ---------------- finish2: out = elu( ds*(sum partials) + ds^2 * z ) ----------------
__global__ __launch_bounds__(256) void k_finish2(const ushort_t* __restrict__ part16,
                                                 const float* __restrict__ ds,
                                                 const float* __restrict__ z,
                                                 float* __restrict__ out) {
    size_t i = (size_t)blockIdx.x * 256 + threadIdx.x;   // 4-elem group index
    const size_t stride = (size_t)NN * CC / 4;           // in ushort4 units
    float s0 = 0.f, s1 = 0.f, s2 = 0.f, s3 = 0.f;
#pragma unroll
    for (int k = 0; k < 4; ++k) {
        ushort4 p = ((const ushort4*)part16)[i + k * stride];
        s0 += bf2f(p.x); s1 += bf2f(p.y); s2 += bf2f(p.z); s3 += bf2f(p.w);
    }
    int row = (int)(i >> 7);
    float d = ds[row];
    float d2 = d * d;
    f32x4 zv = ((const f32x4*)z)[i];
    f32x4 o;
    float v;
    v = d * s0 + d2 * zv[0]; o[0] = v > 0.f ? v : expm1f(v);
    v = d * s1 + d2 * zv[1]; o[1] = v > 0.f ? v : expm1f(v);
    v = d * s2 + d2 * zv[2]; o[2] = v > 0.f ? v : expm1f(v);
    v = d * s3 + d2 * zv[3]; o[3] = v > 0.f ? v : expm1f(v);
    ((f32x4*)out)[i] = o;
}

// ---------------- fallback full-K GEMM1 (f32 A in-kernel convert) + old epilogue ----------------
__global__ __launch_bounds__(256, 4) void k_gemm1_fb(const float* __restrict__ adj,
                                                     const ushort_t* __restrict__ yt,
                                                     const float* __restrict__ ds,
                                                     const float* __restrict__ x,
                                                     ushort_t* __restrict__ mm1) {
    __shared__ __align__(16) ushort_t As[128 * 64];
    __shared__ __align__(16) ushort_t Bs[128 * 64];

    int t = threadIdx.x;
    int wid = t >> 6, lane = t & 63;
    int bid = blockIdx.x;
    bid = (bid & 7) * 32 + (bid >> 3);
    int colBase = (bid & 3) * 128;
    int rowBase = (bid >> 2) * 128;

    int ar = t >> 4;
    int ac4 = t & 15;
    const float* aptr = adj + (size_t)(rowBase + ar) * NN + ac4 * 4;
    int brow0 = t >> 3;
    int bs = t & 7;
    float4 areg[8];

    auto loadA = [&](int kt) {
        const float* p = aptr + kt * 64;
#pragma unroll
        for (int i = 0; i < 8; ++i)
            areg[i] = *(const float4*)(p + (size_t)i * 16 * NN);
    };
    auto writeA = [&]() {
#pragma unroll
        for (int i = 0; i < 8; ++i) {
            int row = i * 16 + ar;
            ushort4 u;
            u.x = f2bf(areg[i].x); u.y = f2bf(areg[i].y);
            u.z = f2bf(areg[i].z); u.w = f2bf(areg[i].w);
            *(ushort4*)((char*)As + row * 128 + ((ac4 * 8) ^ ((row & 7) << 4))) = u;
        }
    };

    f32x4 acc[4][4] = {};
    int wr = wid >> 1, wc = wid & 1;
    int fr = lane & 15, fq = lane >> 4;

    loadA(0);
    for (int kt = 0; kt < NN / 64; ++kt) {
        writeA();
#pragma unroll
        for (int j = 0; j < 4; ++j) {
            int row = j * 32 + brow0;
            gload_lds16((const char*)(yt + (size_t)(colBase + row) * NN + kt * 64 +
                                      ((bs ^ (row & 7)) << 3)),
                        (char*)Bs + j * 4096 + wid * 1024);
        }
        __syncthreads();
        if (kt + 1 < NN / 64) loadA(kt + 1);
#pragma unroll
        for (int ks2 = 0; ks2 < 2; ++ks2) {
            short8 af[4], bf[4];
#pragma unroll
            for (int m = 0; m < 4; ++m) {
                int row = wr * 64 + m * 16 + fr;
                af[m] = *(const short8*)((const char*)As + row * 128 +
                                         ((ks2 * 64 + fq * 16) ^ ((row & 7) << 4)));
            }
#pragma unroll
            for (int n = 0; n < 4; ++n) {
                int col = wc * 64 + n * 16 + fr;
                bf[n] = *(const short8*)((const char*)Bs + col * 128 +
                                         ((ks2 * 64 + fq * 16) ^ ((col & 7) << 4)));
            }
#pragma unroll
            for (int m = 0; m < 4; ++m)
#pragma unroll
                for (int n = 0; n < 4; ++n)
                    acc[m][n] = __builtin_amdgcn_mfma_f32_16x16x32_bf16(af[m], bf[n], acc[m][n], 0, 0, 0);
        }
        __syncthreads();
    }

#pragma unroll
    for (int m = 0; m < 4; ++m) {
#pragma unroll
        for (int j = 0; j < 4; ++j) {
            int gr = rowBase + wr * 64 + m * 16 + fq * 4 + j;
            float dsr = ds[gr];
#pragma unroll
            for (int n = 0; n < 4; ++n) {
                int gc = colBase + wc * 64 + n * 16 + fr;
                float v = dsr * (acc[m][n][j] + dsr * x[(size_t)gr * CC + gc]);
                mm1[(size_t)gr * CC + gc] = f2bf(v);
            }
        }
    }
}

extern "C" void kernel_launch(void* const* d_in, const int* in_sizes, int n_in,
                              void* d_out, int out_size, void* d_ws, size_t ws_size,
                              hipStream_t stream) {
    const float* x   = (const float*)d_in[0];   // [8192][512]
    const float* adj = (const float*)d_in[1];   // [8192][8192]
    const float* w   = (const float*)d_in[2];   // [512][512]
    float* out = (float*)d_out;                 // [8192][512]

    char* ws = (char*)d_ws;
    size_t off = 0;
    float*    ds  = (float*)(ws + off);  off += 32u << 10;               // 32 KB
    ushort_t* yt  = (ushort_t*)(ws + off);  off += 8u << 20;             // 8 MB  [512][8192] (yt2 primary / yt fallback)
    ushort_t* wt  = (ushort_t*)(ws + off);  off += 512u << 10;           // 512 KB
    ushort_t* xb  = (ushort_t*)(ws + off);  off += 8u << 20;             // 8 MB  (xb primary / mm1 fallback)
    float*    z   = (float*)(ws + off);  off += 16u << 20;               // 16 MB f32 [8192][512]
    ushort_t* part16 = (ushort_t*)(ws + off);  off += 32u << 20;         // 32 MB bf16 [4][8192][512]
    ushort_t* adj16  = (ushort_t*)(ws + off);                             // 128 MB
    const size_t adjBytes = (size_t)NN * NN * 2;

    if (ws_size >= off + adjBytes) {
        // ---- primary: z-first algebra + 256^2 phase-interleaved split-K GEMM ----
        k_rowsum_cvt<<<NN, 256, 0, stream>>>(adj, ds, adj16);             // ds + adj16
        k_cvt<<<NN * CC / 4 / 256, 256, 0, stream>>>(x, xb);              // xb = bf16(x)
        k_transpose<<<dim3(CC / 64, CC / 64), 256, 0, stream>>>(w, wt, nullptr, CC, CC);
        k_gemm2t<false><<<256, 256, 0, stream>>>(xb, wt, z);              // z = x @ w (f32)
        k_transpose<<<dim3(NN / 64, CC / 64), 256, 0, stream>>>(z, yt, ds, NN, CC);  // yt2[c][r]=bf16(ds[r]z[r][c])
        k_gemm1d<<<256, 512, 0, stream>>>(adj16, yt, part16);             // part = adj16 @ t
        k_finish2<<<NN * CC / 4 / 256, 256, 0, stream>>>(part16, ds, z, out);
    } else {
        // ---- fallback: original ordering, modest ws ----
        ushort_t* mm1 = xb;
        k_rowsum<<<NN, 256, 0, stream>>>(adj, ds);
        k_transpose<<<dim3(NN / 64, CC / 64), 256, 0, stream>>>(x, yt, ds, NN, CC);
        k_transpose<<<dim3(CC / 64, CC / 64), 256, 0, stream>>>(w, wt, nullptr, CC, CC);
        k_gemm1_fb<<<256, 256, 0, stream>>>(adj, yt, ds, x, mm1);
        k_gemm2t<true><<<256, 256, 0, stream>>>(mm1, wt, out);
    }
}